// Round 10
// baseline (108.469 us; speedup 1.0000x reference)
//
#include <hip/hip_runtime.h>
#include <hip/hip_bf16.h>

#define NB 4096   // batch rows
#define NI 256    // input dim
#define NO 256    // output dim
#define NE 8      // experts

// Device-global scratch. Zeroed by zero_meta_kernel at the start of every
// kernel_launch (no host-side symbol lookups / memsets -> graph-capture safe).
__device__ int g_meta[16];          // [0..7] = per-expert row count, [8] = overflow count
__device__ int g_rowlist[NE * NB];  // per-expert row indices (single-hot rows)
__device__ int g_ovf[NB];           // packed (mask<<16)|row for multi-hot (tie) rows

__global__ void zero_meta_kernel() {
    if (threadIdx.x < 16) g_meta[threadIdx.x] = 0;
}

// ---------------------------------------------------------------------------
// Router: g = sigmoid(x @ Wp^T + bp); mask = experts equal to row max.
// One wave (64 lanes) per row; lane l owns x[b][4l..4l+3].
// ---------------------------------------------------------------------------
__global__ __launch_bounds__(256) void router_kernel(
    const float* __restrict__ x, const float* __restrict__ Wp,
    const float* __restrict__ bp)
{
    __shared__ float wplds[NE * NI];
    const int t = threadIdx.x;
    #pragma unroll
    for (int i = 0; i < NE * NI; i += 256 * 4)
        *(float4*)&wplds[i + t * 4] = *(const float4*)&Wp[i + t * 4];
    __syncthreads();

    const int lane = t & 63;
    const int b = blockIdx.x * 4 + (t >> 6);
    const float4 xv = *(const float4*)&x[b * NI + lane * 4];

    float p[NE];
    #pragma unroll
    for (int e = 0; e < NE; ++e) {
        const float4 wv = *(const float4*)&wplds[e * NI + lane * 4];
        p[e] = xv.x * wv.x + xv.y * wv.y + xv.z * wv.z + xv.w * wv.w;
    }
    // butterfly reduce all 8 partials across the 64-lane wave
    #pragma unroll
    for (int off = 32; off >= 1; off >>= 1) {
        #pragma unroll
        for (int e = 0; e < NE; ++e) p[e] += __shfl_xor(p[e], off);
    }
    float g[NE], gmax = -1e30f;
    #pragma unroll
    for (int e = 0; e < NE; ++e) {
        g[e] = 1.0f / (1.0f + expf(-(p[e] + bp[e])));
        gmax = fmaxf(gmax, g[e]);
    }
    int mask = 0;
    #pragma unroll
    for (int e = 0; e < NE; ++e) mask |= (g[e] == gmax) ? (1 << e) : 0;

    if (lane == 0) {
        if (__popc(mask) == 1) {
            const int e = __ffs(mask) - 1;
            const int pos = atomicAdd(&g_meta[e], 1);
            g_rowlist[e * NB + pos] = b;
        } else {                       // tie: rare slow path
            const int pos = atomicAdd(&g_meta[8], 1);
            g_ovf[pos] = (mask << 16) | b;
        }
    }
}

// ---------------------------------------------------------------------------
// Grouped GEMM over binned rows. Block = 64 rows x 64 cols tile, K=256 in
// kc=16 LDS steps. 256 threads, each owns a 4x4 micro-tile (16 fp32 acc).
// grid.x walks a device-side prefix over per-expert tile counts (max 72).
// ---------------------------------------------------------------------------
__global__ __launch_bounds__(256) void moe_gemm_kernel(
    const float* __restrict__ x, const float* __restrict__ W,
    float* __restrict__ out)
{
    const int T = blockIdx.x;
    const int n0 = blockIdx.y * 64;

    int e = 0, base = 0, cnt = 0;
    for (; e < NE; ++e) {
        cnt = g_meta[e];
        const int te = (cnt + 63) >> 6;
        if (T < base + te) break;
        base += te;
    }
    if (e >= NE) return;                 // beyond total tiles this call
    const int r0 = (T - base) * 64;

    __shared__ int   rlds[64];
    __shared__ float xs[16][68];         // [k][m], padded stride 68 (16B-aligned, conflict-free)
    __shared__ float wst[16][64];        // [k][n]

    const int t = threadIdx.x;
    if (t < 64) {
        const int idx = r0 + t;
        const int bb = g_rowlist[e * NB + min(idx, cnt - 1)];  // cnt>=1 guaranteed here
        rlds[t] = (idx < cnt) ? bb : (bb | 0x40000000);  // bit30 = invalid (tail)
    }
    __syncthreads();

    // staging assignments: one float4 per thread per tile for x and W each
    const int xm = t >> 2, xc = t & 3;   // x tile: row xm (0..63), k-chunk xc (0..3)
    const int wk = t >> 4, wc = t & 15;  // W tile: k-row wk (0..15), n-chunk wc (0..15)
    const float* xptr = x + (rlds[xm] & 0x3FFFFFFF) * NI + xc * 4;
    const float* wptr = W + e * NI * NO + wk * NO + n0 + wc * 4;
    float4 xr = *(const float4*)xptr;
    float4 wr = *(const float4*)wptr;

    const int tm = t >> 4, tn = t & 15;
    float acc[4][4] = {{0.f}};

    #pragma unroll 1
    for (int step = 0; step < 16; ++step) {
        __syncthreads();
        xs[xc * 4 + 0][xm] = xr.x;
        xs[xc * 4 + 1][xm] = xr.y;
        xs[xc * 4 + 2][xm] = xr.z;
        xs[xc * 4 + 3][xm] = xr.w;
        *(float4*)&wst[wk][wc * 4] = wr;
        __syncthreads();
        if (step < 15) {                          // prefetch next K-slab
            xr = *(const float4*)(xptr + (step + 1) * 16);
            wr = *(const float4*)(wptr + (step + 1) * 16 * NO);
        }
        #pragma unroll
        for (int k = 0; k < 16; ++k) {
            const float4 a  = *(const float4*)&xs[k][tm * 4];
            const float4 bv = *(const float4*)&wst[k][tn * 4];
            acc[0][0] += a.x * bv.x; acc[0][1] += a.x * bv.y; acc[0][2] += a.x * bv.z; acc[0][3] += a.x * bv.w;
            acc[1][0] += a.y * bv.x; acc[1][1] += a.y * bv.y; acc[1][2] += a.y * bv.z; acc[1][3] += a.y * bv.w;
            acc[2][0] += a.z * bv.x; acc[2][1] += a.z * bv.y; acc[2][2] += a.z * bv.z; acc[2][3] += a.z * bv.w;
            acc[3][0] += a.w * bv.x; acc[3][1] += a.w * bv.y; acc[3][2] += a.w * bv.z; acc[3][3] += a.w * bv.w;
        }
    }

    #pragma unroll
    for (int r = 0; r < 4; ++r) {
        const int info = rlds[tm * 4 + r];
        if (!(info & 0x40000000)) {
            float4 v;
            v.x = acc[r][0]; v.y = acc[r][1]; v.z = acc[r][2]; v.w = acc[r][3];
            *(float4*)&out[(info & 0x3FFFFFFF) * NO + n0 + tn * 4] = v;
        }
    }
}

// ---------------------------------------------------------------------------
// Overflow (tie) rows: y[b] = sum over tied experts of x[b] @ W[e].
// Expected count ~0; grid-stride so a fixed tiny grid is always correct.
// ---------------------------------------------------------------------------
__global__ __launch_bounds__(256) void ovf_kernel(
    const float* __restrict__ x, const float* __restrict__ W,
    float* __restrict__ out)
{
    __shared__ float xl[NI];
    const int n = g_meta[8];
    for (int idx = blockIdx.x; idx < n; idx += gridDim.x) {
        const int packed = g_ovf[idx];
        const int b = packed & 0xFFFF;
        const int mask = packed >> 16;
        __syncthreads();
        xl[threadIdx.x] = x[b * NI + threadIdx.x];
        __syncthreads();
        float acc = 0.0f;
        for (int e = 0; e < NE; ++e) {
            if (mask & (1 << e)) {
                const float* wp = W + e * NI * NO + threadIdx.x;
                for (int i = 0; i < NI; ++i) acc += xl[i] * wp[i * NO];
            }
        }
        out[b * NO + threadIdx.x] = acc;
    }
}

extern "C" void kernel_launch(void* const* d_in, const int* in_sizes, int n_in,
                              void* d_out, int out_size, void* d_ws, size_t ws_size,
                              hipStream_t stream)
{
    const float* x  = (const float*)d_in[0];
    const float* W  = (const float*)d_in[1];
    const float* Wp = (const float*)d_in[2];
    const float* bp = (const float*)d_in[3];
    float* out = (float*)d_out;

    zero_meta_kernel<<<1, 64, 0, stream>>>();

    router_kernel<<<NB / 4, 256, 0, stream>>>(x, Wp, bp);

    // worst case sum of ceil(cnt_e/64) = (4096 + 8*63)/64 = 71 -> 72 tiles
    dim3 grid(72, 4);
    moe_gemm_kernel<<<grid, 256, 0, stream>>>(x, W, out);

    ovf_kernel<<<16, 256, 0, stream>>>(x, W, out);
}

// Round 11
// 106.656 us; speedup vs baseline: 1.0170x; 1.0170x over previous
//
#include <hip/hip_runtime.h>
#include <hip/hip_bf16.h>

#define NB 4096   // batch rows
#define NI 256    // input dim
#define NO 256    // output dim
#define NE 8      // experts

// Device-global scratch. Invariant: g_meta is ZERO at entry to every call.
// - zero-initialized at module load (first call)
// - re-zeroed at the end of finalize_kernel (every call, incl. graph replays)
// Harness poison only touches d_out/d_ws, never these globals.
__device__ int g_meta[16];          // [0..7] = per-expert row count, [8] = overflow count
__device__ int g_rowlist[NE * NB];  // per-expert row indices (single-hot rows)
__device__ int g_ovf[NB];           // packed (mask<<16)|row for multi-hot (tie) rows

// ---------------------------------------------------------------------------
// Router: g = sigmoid(x @ Wp^T + bp); mask = experts equal to row max.
// One wave (64 lanes) per row; lane l owns x[b][4l..4l+3].
// ---------------------------------------------------------------------------
__global__ __launch_bounds__(256) void router_kernel(
    const float* __restrict__ x, const float* __restrict__ Wp,
    const float* __restrict__ bp)
{
    __shared__ float wplds[NE * NI];
    const int t = threadIdx.x;
    #pragma unroll
    for (int i = 0; i < NE * NI; i += 256 * 4)
        *(float4*)&wplds[i + t * 4] = *(const float4*)&Wp[i + t * 4];
    __syncthreads();

    const int lane = t & 63;
    const int b = blockIdx.x * 4 + (t >> 6);
    const float4 xv = *(const float4*)&x[b * NI + lane * 4];

    float p[NE];
    #pragma unroll
    for (int e = 0; e < NE; ++e) {
        const float4 wv = *(const float4*)&wplds[e * NI + lane * 4];
        p[e] = xv.x * wv.x + xv.y * wv.y + xv.z * wv.z + xv.w * wv.w;
    }
    // butterfly reduce all 8 partials across the 64-lane wave
    #pragma unroll
    for (int off = 32; off >= 1; off >>= 1) {
        #pragma unroll
        for (int e = 0; e < NE; ++e) p[e] += __shfl_xor(p[e], off);
    }
    float g[NE], gmax = -1e30f;
    #pragma unroll
    for (int e = 0; e < NE; ++e) {
        g[e] = 1.0f / (1.0f + expf(-(p[e] + bp[e])));
        gmax = fmaxf(gmax, g[e]);
    }
    int mask = 0;
    #pragma unroll
    for (int e = 0; e < NE; ++e) mask |= (g[e] == gmax) ? (1 << e) : 0;

    if (lane == 0) {
        if (__popc(mask) == 1) {
            const int e = __ffs(mask) - 1;
            const int pos = atomicAdd(&g_meta[e], 1);
            g_rowlist[e * NB + pos] = b;
        } else {                       // tie: rare slow path
            const int pos = atomicAdd(&g_meta[8], 1);
            g_ovf[pos] = (mask << 16) | b;
        }
    }
}

// ---------------------------------------------------------------------------
// Grouped GEMM over binned rows. Block = 64 rows x 64 cols tile, K=256 in
// kc=16 LDS steps. 256 threads, each owns a 4x4 micro-tile (16 fp32 acc).
// grid.x walks a device-side prefix over per-expert tile counts (max 72).
// ---------------------------------------------------------------------------
__global__ __launch_bounds__(256) void moe_gemm_kernel(
    const float* __restrict__ x, const float* __restrict__ W,
    float* __restrict__ out)
{
    const int T = blockIdx.x;
    const int n0 = blockIdx.y * 64;

    int e = 0, base = 0, cnt = 0;
    for (; e < NE; ++e) {
        cnt = g_meta[e];
        const int te = (cnt + 63) >> 6;
        if (T < base + te) break;
        base += te;
    }
    if (e >= NE) return;                 // beyond total tiles this call
    const int r0 = (T - base) * 64;

    __shared__ int   rlds[64];
    __shared__ float xs[16][68];         // [k][m], padded stride 68 (16B-aligned, conflict-free)
    __shared__ float wst[16][64];        // [k][n]

    const int t = threadIdx.x;
    if (t < 64) {
        const int idx = r0 + t;
        const int bb = g_rowlist[e * NB + min(idx, cnt - 1)];  // cnt>=1 guaranteed here
        rlds[t] = (idx < cnt) ? bb : (bb | 0x40000000);  // bit30 = invalid (tail)
    }
    __syncthreads();

    // staging assignments: one float4 per thread per tile for x and W each
    const int xm = t >> 2, xc = t & 3;   // x tile: row xm (0..63), k-chunk xc (0..3)
    const int wk = t >> 4, wc = t & 15;  // W tile: k-row wk (0..15), n-chunk wc (0..15)
    const float* xptr = x + (rlds[xm] & 0x3FFFFFFF) * NI + xc * 4;
    const float* wptr = W + e * NI * NO + wk * NO + n0 + wc * 4;
    float4 xr = *(const float4*)xptr;
    float4 wr = *(const float4*)wptr;

    const int tm = t >> 4, tn = t & 15;
    float acc[4][4] = {{0.f}};

    #pragma unroll 1
    for (int step = 0; step < 16; ++step) {
        __syncthreads();
        xs[xc * 4 + 0][xm] = xr.x;
        xs[xc * 4 + 1][xm] = xr.y;
        xs[xc * 4 + 2][xm] = xr.z;
        xs[xc * 4 + 3][xm] = xr.w;
        *(float4*)&wst[wk][wc * 4] = wr;
        __syncthreads();
        if (step < 15) {                          // prefetch next K-slab
            xr = *(const float4*)(xptr + (step + 1) * 16);
            wr = *(const float4*)(wptr + (step + 1) * 16 * NO);
        }
        #pragma unroll
        for (int k = 0; k < 16; ++k) {
            const float4 a  = *(const float4*)&xs[k][tm * 4];
            const float4 bv = *(const float4*)&wst[k][tn * 4];
            acc[0][0] += a.x * bv.x; acc[0][1] += a.x * bv.y; acc[0][2] += a.x * bv.z; acc[0][3] += a.x * bv.w;
            acc[1][0] += a.y * bv.x; acc[1][1] += a.y * bv.y; acc[1][2] += a.y * bv.z; acc[1][3] += a.y * bv.w;
            acc[2][0] += a.z * bv.x; acc[2][1] += a.z * bv.y; acc[2][2] += a.z * bv.z; acc[2][3] += a.z * bv.w;
            acc[3][0] += a.w * bv.x; acc[3][1] += a.w * bv.y; acc[3][2] += a.w * bv.z; acc[3][3] += a.w * bv.w;
        }
    }

    #pragma unroll
    for (int r = 0; r < 4; ++r) {
        const int info = rlds[tm * 4 + r];
        if (!(info & 0x40000000)) {
            float4 v;
            v.x = acc[r][0]; v.y = acc[r][1]; v.z = acc[r][2]; v.w = acc[r][3];
            *(float4*)&out[(info & 0x3FFFFFFF) * NO + n0 + tn * 4] = v;
        }
    }
}

// ---------------------------------------------------------------------------
// Finalize: (a) tie rows (expected 0): y[b] = sum of tied experts' x[b]@W[e];
// (b) re-zero g_meta for the next call. SINGLE block => all readers of
// g_meta[8] are in this block; __syncthreads orders reads before the zeroing.
// Runs after moe_gemm_kernel (stream order), so no other reader exists.
// ---------------------------------------------------------------------------
__global__ __launch_bounds__(256) void finalize_kernel(
    const float* __restrict__ x, const float* __restrict__ W,
    float* __restrict__ out)
{
    __shared__ float xl[NI];
    const int n = g_meta[8];              // every thread reads before any zeroing
    for (int idx = 0; idx < n; ++idx) {
        const int packed = g_ovf[idx];
        const int b = packed & 0xFFFF;
        const int mask = packed >> 16;
        __syncthreads();
        xl[threadIdx.x] = x[b * NI + threadIdx.x];
        __syncthreads();
        float acc = 0.0f;
        for (int e = 0; e < NE; ++e) {
            if (mask & (1 << e)) {
                const float* wp = W + e * NI * NO + threadIdx.x;
                for (int i = 0; i < NI; ++i) acc += xl[i] * wp[i * NO];
            }
        }
        out[b * NO + threadIdx.x] = acc;
    }
    __syncthreads();                      // all threads done reading g_meta
    if (threadIdx.x < 16) g_meta[threadIdx.x] = 0;   // ready for next call
}

extern "C" void kernel_launch(void* const* d_in, const int* in_sizes, int n_in,
                              void* d_out, int out_size, void* d_ws, size_t ws_size,
                              hipStream_t stream)
{
    const float* x  = (const float*)d_in[0];
    const float* W  = (const float*)d_in[1];
    const float* Wp = (const float*)d_in[2];
    const float* bp = (const float*)d_in[3];
    float* out = (float*)d_out;

    router_kernel<<<NB / 4, 256, 0, stream>>>(x, Wp, bp);

    // worst case sum of ceil(cnt_e/64) = (4096 + 8*63)/64 = 71 -> 72 tiles
    dim3 grid(72, 4);
    moe_gemm_kernel<<<grid, 256, 0, stream>>>(x, W, out);

    finalize_kernel<<<1, 256, 0, stream>>>(x, W, out);
}